// Round 2
// baseline (580.242 us; speedup 1.0000x reference)
//
#include <hip/hip_runtime.h>

typedef __bf16 bf16;
typedef __attribute__((ext_vector_type(8))) __bf16 bf16x8;
typedef __attribute__((ext_vector_type(4))) float floatx4;

typedef const void __attribute__((address_space(1)))* gas1p;
typedef void __attribute__((address_space(3)))* las3p;

#define LOG2E 1.44269504088896340736f

static constexpr int D_MODEL = 1024;
static constexpr int N_HEADS = 16;
static constexpr int HDIM    = 64;
static constexpr int BSZ     = 8;
static constexpr int SEQ     = 1024;
static constexpr int ROWS    = BSZ * SEQ;   // 8192
static constexpr int FF_IN   = 1088;        // 17*64
static constexpr int FF_HID  = 2048;

__device__ __forceinline__ floatx4 mfma_bf16(bf16x8 a, bf16x8 b, floatx4 c) {
  return __builtin_amdgcn_mfma_f32_16x16x32_bf16(a, b, c, 0, 0, 0);
}

__device__ __forceinline__ float flex_load(const void* src, size_t idx, int isbf) {
  return isbf ? (float)((const bf16*)src)[idx] : ((const float*)src)[idx];
}

// ---------------- dtype detection ----------------
// For a bf16 array of ~N(0,1) data, bits[14:8] of each 32-bit word (= exponent
// field of the low-half bf16) cluster in [0x3B,0x41]. For fp32 those are
// uniform mantissa bits. Vote over 4096 sampled words; flag=1 means bf16.
__global__ void detect_kernel(const unsigned* __restrict__ w, int* __restrict__ flag) {
  __shared__ int cnt;
  if (threadIdx.x == 0) cnt = 0;
  __syncthreads();
  int hits = 0;
  for (int i = threadIdx.x; i < 4096; i += 256) {
    const unsigned v = w[(size_t)i * 997 + 13];   // max idx ~4.08M < 4.19M words
    const unsigned b = (v >> 8) & 0x7F;
    hits += (b >= 0x3B && b <= 0x41) ? 1 : 0;
  }
  atomicAdd(&cnt, hits);
  __syncthreads();
  if (threadIdx.x == 0) *flag = (cnt > 2048) ? 1 : 0;
}

// ---------------- converters ----------------
__global__ __launch_bounds__(256)
void to_bf16_kernel(const void* __restrict__ src, bf16* __restrict__ dst, int n,
                    const int* __restrict__ flag) {
  const int isbf = *flag;
  const int i = blockIdx.x * 256 + threadIdx.x;
  if (i < n) dst[i] = (bf16)flex_load(src, i, isbf);
}

__global__ __launch_bounds__(256)
void to_f32_kernel(const void* __restrict__ src, float* __restrict__ dst, int n,
                   const int* __restrict__ flag) {
  const int isbf = *flag;
  const int i = blockIdx.x * 256 + threadIdx.x;
  if (i < n) dst[i] = flex_load(src, i, isbf);
}

__global__ __launch_bounds__(256)
void store_out_kernel(const float* __restrict__ src, void* __restrict__ dst, int n,
                      const int* __restrict__ flag) {
  const int isbf = *flag;
  const int i = blockIdx.x * 256 + threadIdx.x;
  if (i < n) {
    if (isbf) ((bf16*)dst)[i] = (bf16)src[i];
    else      ((float*)dst)[i] = src[i];
  }
}

// ---------------- weight transpose (+optional scale), flag-aware load ----------------
// dst[C][R] = src[R][C] * scale.  R,C multiples of 32.
__global__ __launch_bounds__(256)
void transpose_scale_kernel(const void* __restrict__ src, bf16* __restrict__ dst,
                            int R, int C, float scale, const int* __restrict__ flag) {
  __shared__ float tile[32][33];
  const int isbf = *flag;
  const int c0 = blockIdx.x * 32, r0 = blockIdx.y * 32;
  const int tx = threadIdx.x & 31, ty = threadIdx.x >> 5;
  for (int i = ty; i < 32; i += 8)
    tile[i][tx] = flex_load(src, (size_t)(r0 + i) * C + (c0 + tx), isbf);
  __syncthreads();
  for (int i = ty; i < 32; i += 8)
    dst[(size_t)(c0 + i) * R + (r0 + tx)] = (bf16)(tile[tx][i] * scale);
}

// v [b, i, h, d] (= [8192, 1024] bf16) -> vt [b, h, d, i]
__global__ __launch_bounds__(256)
void transpose_v_kernel(const bf16* __restrict__ v, bf16* __restrict__ vt) {
  __shared__ float tile[32][33];
  const int bh = blockIdx.z, b = bh >> 4, h = bh & 15;
  const int s0 = blockIdx.x * 32, d0 = blockIdx.y * 32;
  const int tx = threadIdx.x & 31, ty = threadIdx.x >> 5;
  const bf16* src = v + (size_t)b * SEQ * D_MODEL + h * HDIM;
  bf16* dst = vt + (size_t)bh * HDIM * SEQ;
  for (int i = ty; i < 32; i += 8)
    tile[i][tx] = (float)src[(size_t)(s0 + i) * D_MODEL + d0 + tx];
  __syncthreads();
  for (int i = ty; i < 32; i += 8)
    dst[(size_t)(d0 + i) * SEQ + s0 + tx] = (bf16)tile[tx][i];
}

// ---------------- GEMM: C[M,N] = A[M,K] @ BT[N,K]^T + bias (opt ReLU) ----------------
// m97 structure: 128xBN tile, BK=32, 4 waves (2x2), global_load_lds width-16 staging.
template <int BN, bool DO_RELU, bool OUT_F32>
__global__ __launch_bounds__(256)
void gemm_bt(const bf16* __restrict__ A, const bf16* __restrict__ BT,
             const float* __restrict__ bias, float bias_scale,
             void* __restrict__ Cv, int M, int N, int K, int ldc) {
  constexpr int BM = 128, BK = 32;
  constexpr int TCN = BN / 32;               // tile-cols per wave
  constexpr int ACH = (BM * BK) / (256 * 8); // 2 chunks/thread for A
  constexpr int BCH = (BN * BK) / (256 * 8); // 2 (BN=128) or 1 (BN=64)
  __shared__ bf16 As[BM * BK];
  __shared__ bf16 Bs[BN * BK];
  const int tid = threadIdx.x;
  const int wave = tid >> 6, lane = tid & 63;
  const int quad = lane >> 4, lo = lane & 15;
  const int wm = wave >> 1, wn = wave & 1;
  const int m0 = blockIdx.x * BM;
  const int n0 = blockIdx.y * BN;

  floatx4 acc[4][TCN];
#pragma unroll
  for (int i = 0; i < 4; i++)
#pragma unroll
    for (int j = 0; j < TCN; j++) acc[i][j] = floatx4{0.f, 0.f, 0.f, 0.f};

  for (int kb = 0; kb < K; kb += BK) {
#pragma unroll
    for (int u = 0; u < ACH; u++) {
      const int c = u * 256 + tid;                 // LDS dest = c*16B (lane-contig per wave)
      const int row = c >> 2, cc = c & 3;
      const bf16* g = A + (size_t)(m0 + row) * K + kb + cc * 8;
      __builtin_amdgcn_global_load_lds((gas1p)g, (las3p)(As + c * 8), 16, 0, 0);
    }
#pragma unroll
    for (int u = 0; u < BCH; u++) {
      const int c = u * 256 + tid;
      const int row = c >> 2, cc = c & 3;
      const bf16* g = BT + (size_t)(n0 + row) * K + kb + cc * 8;
      __builtin_amdgcn_global_load_lds((gas1p)g, (las3p)(Bs + c * 8), 16, 0, 0);
    }
    __syncthreads();
    bf16x8 af[4], bfr[TCN];
#pragma unroll
    for (int tr = 0; tr < 4; tr++)
      af[tr] = *reinterpret_cast<const bf16x8*>(As + (wm * 64 + tr * 16 + lo) * BK + quad * 8);
#pragma unroll
    for (int tc = 0; tc < TCN; tc++)
      bfr[tc] = *reinterpret_cast<const bf16x8*>(Bs + (wn * (BN / 2) + tc * 16 + lo) * BK + quad * 8);
#pragma unroll
    for (int tr = 0; tr < 4; tr++)
#pragma unroll
      for (int tc = 0; tc < TCN; tc++)
        acc[tr][tc] = mfma_bf16(af[tr], bfr[tc], acc[tr][tc]);
    __syncthreads();
  }

#pragma unroll
  for (int tc = 0; tc < TCN; tc++) {
    const int col = n0 + wn * (BN / 2) + tc * 16 + lo;
    const float bval = bias[col] * bias_scale;
#pragma unroll
    for (int tr = 0; tr < 4; tr++) {
      const int rbase = m0 + wm * 64 + tr * 16 + quad * 4;
#pragma unroll
      for (int r = 0; r < 4; r++) {
        float v = acc[tr][tc][r] + bval;
        if (DO_RELU) v = fmaxf(v, 0.f);
        if (OUT_F32) ((float*)Cv)[(size_t)(rbase + r) * ldc + col] = v;
        else         ((bf16*)Cv)[(size_t)(rbase + r) * ldc + col] = (bf16)v;
      }
    }
  }
}

// ---------------- flash attention ----------------
// grid (SEQ/128, BSZ*N_HEADS). Per block: 128 q-rows of one (b,h).
// q pre-scaled by 1/8 (folded in weights). Diagonal masked.
__global__ __launch_bounds__(256)
void attn_kernel(const bf16* __restrict__ Q, const bf16* __restrict__ Kmat,
                 const bf16* __restrict__ Vt, bf16* __restrict__ Cc) {
  constexpr int TQ = 128, TJ = 64;
  __shared__ bf16 Ks[TJ][HDIM + 8];
  __shared__ bf16 Vs[HDIM][TJ + 8];
  __shared__ bf16 Ps[TQ][TJ + 8];
  const int bh = blockIdx.y, b = bh >> 4, h = bh & 15;
  const int i0 = blockIdx.x * TQ;
  const int tid = threadIdx.x, wave = tid >> 6, lane = tid & 63;
  const int quad = lane >> 4, lo = lane & 15;
  const bf16* qptr = Q + (size_t)b * SEQ * D_MODEL + h * HDIM;
  const bf16* kptr = Kmat + (size_t)b * SEQ * D_MODEL + h * HDIM;
  const bf16* vptr = Vt + (size_t)bh * HDIM * SEQ;

  bf16x8 qf[2][2];
#pragma unroll
  for (int tr = 0; tr < 2; tr++)
#pragma unroll
    for (int kf = 0; kf < 2; kf++)
      qf[tr][kf] = *reinterpret_cast<const bf16x8*>(
          qptr + (size_t)(i0 + wave * 32 + tr * 16 + lo) * D_MODEL + kf * 32 + quad * 8);

  floatx4 oacc[2][4];
  float mrow[2][4], lrow[2][4];
#pragma unroll
  for (int tr = 0; tr < 2; tr++) {
#pragma unroll
    for (int td = 0; td < 4; td++) oacc[tr][td] = floatx4{0.f, 0.f, 0.f, 0.f};
#pragma unroll
    for (int r = 0; r < 4; r++) { mrow[tr][r] = -1e30f; lrow[tr][r] = 0.f; }
  }

  for (int jb = 0; jb < SEQ / TJ; jb++) {
#pragma unroll
    for (int u = 0; u < 2; u++) {
      const int c = u * 256 + tid;
      const int row = c >> 3, cc = c & 7;
      *reinterpret_cast<bf16x8*>(&Ks[row][cc * 8]) =
          *reinterpret_cast<const bf16x8*>(kptr + (size_t)(jb * TJ + row) * D_MODEL + cc * 8);
      *reinterpret_cast<bf16x8*>(&Vs[row][cc * 8]) =
          *reinterpret_cast<const bf16x8*>(vptr + (size_t)row * SEQ + jb * TJ + cc * 8);
    }
    __syncthreads();

    bf16x8 kfr[4][2];
#pragma unroll
    for (int tc = 0; tc < 4; tc++)
#pragma unroll
      for (int kf = 0; kf < 2; kf++)
        kfr[tc][kf] = *reinterpret_cast<const bf16x8*>(&Ks[tc * 16 + lo][kf * 32 + quad * 8]);
    floatx4 sacc[2][4];
#pragma unroll
    for (int tr = 0; tr < 2; tr++)
#pragma unroll
      for (int tc = 0; tc < 4; tc++) sacc[tr][tc] = floatx4{0.f, 0.f, 0.f, 0.f};
#pragma unroll
    for (int tr = 0; tr < 2; tr++)
#pragma unroll
      for (int tc = 0; tc < 4; tc++)
#pragma unroll
        for (int kf = 0; kf < 2; kf++)
          sacc[tr][tc] = mfma_bf16(qf[tr][kf], kfr[tc][kf], sacc[tr][tc]);

#pragma unroll
    for (int tr = 0; tr < 2; tr++) {
      const int ibase = i0 + wave * 32 + tr * 16 + quad * 4;
#pragma unroll
      for (int r = 0; r < 4; r++) {
        const int ig = ibase + r;
#pragma unroll
        for (int tc = 0; tc < 4; tc++) {
          const int jg = jb * TJ + tc * 16 + lo;
          if (jg == ig) sacc[tr][tc][r] = -1e30f;
        }
        float rm = fmaxf(fmaxf(sacc[tr][0][r], sacc[tr][1][r]),
                         fmaxf(sacc[tr][2][r], sacc[tr][3][r]));
        rm = fmaxf(rm, __shfl_xor(rm, 1));
        rm = fmaxf(rm, __shfl_xor(rm, 2));
        rm = fmaxf(rm, __shfl_xor(rm, 4));
        rm = fmaxf(rm, __shfl_xor(rm, 8));
        const float mnew = fmaxf(mrow[tr][r], rm);
        const float alpha = exp2f((mrow[tr][r] - mnew) * LOG2E);
        mrow[tr][r] = mnew;
        float rs = 0.f;
#pragma unroll
        for (int tc = 0; tc < 4; tc++) {
          const float p = exp2f((sacc[tr][tc][r] - mnew) * LOG2E);
          sacc[tr][tc][r] = p;
          rs += p;
        }
        rs += __shfl_xor(rs, 1);
        rs += __shfl_xor(rs, 2);
        rs += __shfl_xor(rs, 4);
        rs += __shfl_xor(rs, 8);
        lrow[tr][r] = lrow[tr][r] * alpha + rs;
#pragma unroll
        for (int td = 0; td < 4; td++) oacc[tr][td][r] *= alpha;
#pragma unroll
        for (int tc = 0; tc < 4; tc++)
          Ps[wave * 32 + tr * 16 + quad * 4 + r][tc * 16 + lo] = (bf16)sacc[tr][tc][r];
      }
    }
    // each wave reads back only its OWN Ps rows -> same-wave LDS RAW, no barrier
    bf16x8 pf[2][2];
#pragma unroll
    for (int tr = 0; tr < 2; tr++)
#pragma unroll
      for (int kf = 0; kf < 2; kf++)
        pf[tr][kf] = *reinterpret_cast<const bf16x8*>(&Ps[wave * 32 + tr * 16 + lo][kf * 32 + quad * 8]);
#pragma unroll
    for (int td = 0; td < 4; td++)
#pragma unroll
      for (int kf = 0; kf < 2; kf++) {
        const bf16x8 vfr = *reinterpret_cast<const bf16x8*>(&Vs[td * 16 + lo][kf * 32 + quad * 8]);
#pragma unroll
        for (int tr = 0; tr < 2; tr++)
          oacc[tr][td] = mfma_bf16(pf[tr][kf], vfr, oacc[tr][td]);
      }
    __syncthreads();
  }

#pragma unroll
  for (int tr = 0; tr < 2; tr++)
#pragma unroll
    for (int r = 0; r < 4; r++) {
      const int ig = i0 + wave * 32 + tr * 16 + quad * 4 + r;
      const float inv = 1.0f / lrow[tr][r];
      const size_t base = ((size_t)b * SEQ + ig) * FF_IN + h * HDIM;
#pragma unroll
      for (int td = 0; td < 4; td++)
        Cc[base + td * 16 + lo] = (bf16)(oacc[tr][td][r] * inv);
    }
}

// ---------------- launch ----------------
extern "C" void kernel_launch(void* const* d_in, const int* in_sizes, int n_in,
                              void* d_out, int out_size, void* d_ws, size_t ws_size,
                              hipStream_t stream) {
  (void)in_sizes; (void)n_in; (void)ws_size;
  const void* x   = d_in[0];
  const void* Wq  = d_in[1];
  const void* bq  = d_in[2];
  const void* Wk  = d_in[3];
  const void* bk  = d_in[4];
  const void* Wv  = d_in[5];
  const void* bv  = d_in[6];
  const void* Win = d_in[7];
  const void* bin = d_in[8];
  const void* W1  = d_in[9];
  const void* b1  = d_in[10];
  const void* W2  = d_in[11];
  const void* b2  = d_in[12];

  size_t off = 0;
  char* wsb = (char*)d_ws;
  auto alloc = [&](size_t bytes) {
    void* p = (void*)(wsb + off);
    off += (bytes + 255) & ~(size_t)255;
    return p;
  };
  int*   flag = (int*)alloc(4);
  bf16*  xbf  = (bf16*)alloc((size_t)ROWS * D_MODEL * 2);
  bf16*  WqT  = (bf16*)alloc((size_t)1024 * 1024 * 2);
  bf16*  WkT  = (bf16*)alloc((size_t)1024 * 1024 * 2);
  bf16*  WvT  = (bf16*)alloc((size_t)1024 * 1024 * 2);
  bf16*  WinT = (bf16*)alloc((size_t)64 * 1024 * 2);
  bf16*  W1T  = (bf16*)alloc((size_t)FF_HID * FF_IN * 2);
  bf16*  W2T  = (bf16*)alloc((size_t)D_MODEL * FF_HID * 2);
  float* bqf  = (float*)alloc(1024 * 4);
  float* bkf  = (float*)alloc(1024 * 4);
  float* bvf  = (float*)alloc(1024 * 4);
  float* binf = (float*)alloc(64 * 4);
  float* b1f  = (float*)alloc(FF_HID * 4);
  float* b2f  = (float*)alloc(D_MODEL * 4);
  bf16*  qbuf = (bf16*)alloc((size_t)ROWS * D_MODEL * 2);
  bf16*  kbuf = (bf16*)alloc((size_t)ROWS * D_MODEL * 2);
  bf16*  vbuf = (bf16*)alloc((size_t)ROWS * D_MODEL * 2);
  bf16*  vtb  = (bf16*)alloc((size_t)ROWS * D_MODEL * 2);
  bf16*  cbuf = (bf16*)alloc((size_t)ROWS * FF_IN * 2);
  bf16*  hbuf = (bf16*)alloc((size_t)ROWS * FF_HID * 2);
  float* obuf = (float*)alloc((size_t)ROWS * D_MODEL * 4);

  const dim3 blk(256);
  detect_kernel<<<1, blk, 0, stream>>>((const unsigned*)x, flag);

  to_bf16_kernel<<<(ROWS * D_MODEL) / 256, blk, 0, stream>>>(x, xbf, ROWS * D_MODEL, flag);
  to_f32_kernel<<<4, blk, 0, stream>>>(bq, bqf, 1024, flag);
  to_f32_kernel<<<4, blk, 0, stream>>>(bk, bkf, 1024, flag);
  to_f32_kernel<<<4, blk, 0, stream>>>(bv, bvf, 1024, flag);
  to_f32_kernel<<<1, blk, 0, stream>>>(bin, binf, 64, flag);
  to_f32_kernel<<<8, blk, 0, stream>>>(b1, b1f, FF_HID, flag);
  to_f32_kernel<<<4, blk, 0, stream>>>(b2, b2f, D_MODEL, flag);

  // weight transposes (q scale 1/8 folded into WqT; bq scaled at GEMM)
  transpose_scale_kernel<<<dim3(32, 32), blk, 0, stream>>>(Wq, WqT, 1024, 1024, 0.125f, flag);
  transpose_scale_kernel<<<dim3(32, 32), blk, 0, stream>>>(Wk, WkT, 1024, 1024, 1.0f, flag);
  transpose_scale_kernel<<<dim3(32, 32), blk, 0, stream>>>(Wv, WvT, 1024, 1024, 1.0f, flag);
  transpose_scale_kernel<<<dim3(2, 32),  blk, 0, stream>>>(Win, WinT, 1024, 64, 1.0f, flag);
  transpose_scale_kernel<<<dim3(64, 34), blk, 0, stream>>>(W1, W1T, FF_IN, FF_HID, 1.0f, flag);
  transpose_scale_kernel<<<dim3(32, 64), blk, 0, stream>>>(W2, W2T, FF_HID, D_MODEL, 1.0f, flag);

  // projections
  gemm_bt<128, false, false><<<dim3(ROWS / 128, 1024 / 128), blk, 0, stream>>>(
      xbf, WqT, bqf, 0.125f, qbuf, ROWS, 1024, 1024, 1024);
  gemm_bt<128, false, false><<<dim3(ROWS / 128, 1024 / 128), blk, 0, stream>>>(
      xbf, WkT, bkf, 1.0f, kbuf, ROWS, 1024, 1024, 1024);
  gemm_bt<128, false, false><<<dim3(ROWS / 128, 1024 / 128), blk, 0, stream>>>(
      xbf, WvT, bvf, 1.0f, vbuf, ROWS, 1024, 1024, 1024);
  gemm_bt<64, false, false><<<dim3(ROWS / 128, 1), blk, 0, stream>>>(
      xbf, WinT, binf, 1.0f, cbuf + 1024, ROWS, 64, 1024, FF_IN);

  transpose_v_kernel<<<dim3(SEQ / 32, HDIM / 32, BSZ * N_HEADS), blk, 0, stream>>>(vbuf, vtb);

  attn_kernel<<<dim3(SEQ / 128, BSZ * N_HEADS), blk, 0, stream>>>(qbuf, kbuf, vtb, cbuf);

  // FFN
  gemm_bt<128, true, false><<<dim3(ROWS / 128, FF_HID / 128), blk, 0, stream>>>(
      cbuf, W1T, b1f, 1.0f, hbuf, ROWS, FF_HID, FF_IN, FF_HID);
  gemm_bt<128, false, true><<<dim3(ROWS / 128, D_MODEL / 128), blk, 0, stream>>>(
      hbuf, W2T, b2f, 1.0f, obuf, ROWS, D_MODEL, FF_HID, D_MODEL);

  store_out_kernel<<<(ROWS * D_MODEL) / 256, blk, 0, stream>>>(obuf, d_out, out_size, flag);
}